// Round 8
// baseline (255.825 us; speedup 1.0000x reference)
//
#include <hip/hip_runtime.h>

// Problem constants
constexpr int B    = 32;
constexpr int N    = 1568;
constexpr int N0   = 3136;
constexpr int Nt   = 784;
constexpr int Cin  = 256;
constexpr int Cout = 512;
constexpr int H    = 56;
constexpr int W    = 56;
constexpr int HW   = 3136;
constexpr int Ho   = 28;
constexpr int Wo   = 28;
constexpr int HWo  = 784;
constexpr int RR   = B * Nt;      // 25088 GEMM rows
constexpr int NE   = B * N0;      // 100352 entries per index list
constexpr int NBP  = B * HW;      // 100352 input-pixel COUNT bins (not scanned)
constexpr int NBT  = B * Nt;      // 25088 token bins   (scanned, first)
constexpr int NBO  = B * HWo;     // 25088 conv-window bins (scanned, second)
constexpr int SB   = NBT + NBO;   // 50176 scanned bins
constexpr int NCHUNK = SB / 256;  // 196
constexpr int NG   = 32;          // BN1 partial spread factor

// Workspace layout (4-byte words). hist + BN partials contiguous -> one memset.
constexpr size_t W_HISTP = 0;                          // NBP ints (zeroed)
constexpr size_t W_HISTS = NBP;                        // SB ints (zeroed)
constexpr size_t W_S2SUM = NBP + SB;                   // 512
constexpr size_t W_S2SQ  = W_S2SUM + Cout;             // 512
constexpr size_t W_S1P   = W_S2SQ + Cout;              // NG*256
constexpr size_t W_S1QP  = W_S1P + (size_t)NG * Cin;   // NG*256 (memset region ends)
constexpr size_t W_MEND  = W_S1QP + (size_t)NG * Cin;
constexpr size_t W_OFF   = W_MEND;                     // SB+1 ints (+pad)
constexpr size_t W_CUR   = W_OFF + SB + 8;             // SB ints
constexpr size_t W_PC    = W_CUR + SB;                 // NE ints (p56 | p28<<16)
constexpr size_t W_BSUM  = W_PC + NE;                  // 512 ints
constexpr size_t W_LT    = W_BSUM + 512;               // NE int2 -> 2*NE words
constexpr size_t W_LC    = W_LT + (size_t)2 * NE;      // up to 4*NE int2 -> 8*NE words
constexpr size_t W_CONVB = W_LC + (size_t)8 * NE;      // B*HWo*Cin bf16 -> /2 words
constexpr size_t W_YBF   = W_CONVB + (size_t)B * HWo * Cin / 2;  // RR*Cin bf16
constexpr size_t W_WFB   = W_YBF + (size_t)RR * Cin / 2;         // Cout*Cin bf16
constexpr size_t W_BIAS  = W_WFB + (size_t)Cout * Cin / 2;       // 512
constexpr size_t W_ZB    = W_BIAS + Cout;              // RR*Cout bf16 -> /2 words

__device__ __forceinline__ int pix_of(float t, float scale) {
    t = fminf(fmaxf(t, -1.0f), 1.0f);
    float u = __fadd_rn(__fmul_rn(t, 0.5f), 0.5f);   // no fma contraction
    return (int)rintf(__fmul_rn(u, scale));          // round-half-even == jnp.round
}
__device__ __forceinline__ unsigned short f2bf(float f) {
    unsigned int u = __float_as_uint(f);
    u = (u + 0x7fffu + ((u >> 16) & 1u)) >> 16;      // RNE
    return (unsigned short)u;
}
__device__ __forceinline__ float bf2f(unsigned short h) {
    return __uint_as_float(((unsigned int)h) << 16);
}
__device__ __forceinline__ void gload_lds16(const void* g, void* lds) {
    __builtin_amdgcn_global_load_lds(
        (const __attribute__((address_space(1))) void*)g,
        (__attribute__((address_space(3))) void*)lds, 16, 0, 0);
}

// ---- sort phase -------------------------------------------------------------
__global__ void k_hist(const float* __restrict__ loc, const int* __restrict__ idxt,
                       int* __restrict__ histP, int* __restrict__ histS,
                       int* __restrict__ pc) {
    int i = blockIdx.x * 256 + threadIdx.x;
    if (i >= NE) return;
    int b = i / N0;
    float lx = loc[(size_t)2 * i], ly = loc[(size_t)2 * i + 1];
    int ix = pix_of(lx, 55.0f), iy = pix_of(ly, 55.0f);
    int jx = pix_of(lx, 27.0f), jy = pix_of(ly, 27.0f);
    int p56 = iy * W + ix, p28 = jy * Wo + jx;
    pc[i] = p56 | (p28 << 16);
    atomicAdd(&histP[b * HW + p56], 1);
    atomicAdd(&histS[b * Nt + idxt[i]], 1);
    int oy_lo = iy >> 1, oy_hi = min(Ho - 1, (iy + 1) >> 1);
    int ox_lo = ix >> 1, ox_hi = min(Wo - 1, (ix + 1) >> 1);
    for (int oy = oy_lo; oy <= oy_hi; ++oy)
        for (int ox = ox_lo; ox <= ox_hi; ++ox)
            atomicAdd(&histS[NBT + b * HWo + oy * Wo + ox], 1);
}

__global__ void k_scanA(const int* __restrict__ hist, int* __restrict__ bsum) {
    __shared__ int sm[256];
    int i = blockIdx.x * 256 + threadIdx.x;
    sm[threadIdx.x] = hist[i];
    __syncthreads();
    for (int d = 128; d > 0; d >>= 1) {
        if (threadIdx.x < d) sm[threadIdx.x] += sm[threadIdx.x + d];
        __syncthreads();
    }
    if (threadIdx.x == 0) bsum[blockIdx.x] = sm[0];
}

__global__ void k_scanB(int* __restrict__ bsum) {
    __shared__ int sm[512];
    int t = threadIdx.x;
    int v = (t < NCHUNK) ? bsum[t] : 0;
    sm[t] = v; __syncthreads();
    for (int d = 1; d < 512; d <<= 1) {
        int u = (t >= d) ? sm[t - d] : 0;
        __syncthreads();
        sm[t] += u;
        __syncthreads();
    }
    if (t < NCHUNK) bsum[t] = sm[t] - v;
}

__global__ void k_scanC(const int* __restrict__ hist, const int* __restrict__ bsum,
                        int* __restrict__ off, int* __restrict__ cur) {
    __shared__ int sm[256];
    int t = threadIdx.x;
    int i = blockIdx.x * 256 + t;
    int v = hist[i];
    sm[t] = v; __syncthreads();
    for (int d = 1; d < 256; d <<= 1) {
        int u = (t >= d) ? sm[t - d] : 0;
        __syncthreads();
        sm[t] += u;
        __syncthreads();
    }
    int excl = bsum[blockIdx.x] + sm[t] - v;
    off[i] = excl; cur[i] = excl;
    if (i == SB - 1) off[SB] = excl + v;
}

__global__ void k_scat(const int* __restrict__ pc, const int* __restrict__ idxa,
                       const int* __restrict__ idxt, const float* __restrict__ wt,
                       const int* __restrict__ histP, int* __restrict__ cur,
                       int2* __restrict__ listT, int2* __restrict__ listC) {
    int i = blockIdx.x * 256 + threadIdx.x;
    if (i >= NE) return;
    int b = i / N0;
    int v = pc[i];
    int p56 = v & 0xFFFF, p28 = v >> 16;
    int s = idxa[i];
    int posT = atomicAdd(&cur[b * Nt + idxt[i]], 1);
    listT[posT] = make_int2(s | (p28 << 16), __float_as_int(wt[i]));
    float wrc = 1.0f / ((float)histP[b * HW + p56] + 1e-6f);
    int wrci = __float_as_int(wrc);
    int iy = p56 / W, ix = p56 - iy * W;
    int oy_lo = iy >> 1, oy_hi = min(Ho - 1, (iy + 1) >> 1);
    int ox_lo = ix >> 1, ox_hi = min(Wo - 1, (ix + 1) >> 1);
    for (int oy = oy_lo; oy <= oy_hi; ++oy)
        for (int ox = ox_lo; ox <= ox_hi; ++ox) {
            int tap = (iy - (2 * oy - 1)) * 3 + (ix - (2 * ox - 1));
            int posC = atomicAdd(&cur[NBT + b * HWo + oy * Wo + ox], 1) - NE;
            listC[posC] = make_int2(s | (tap << 16), wrci);
        }
}

// ---- fused token2map + 3x3 dw s2 conv ---------------------------------------
// wave per output pixel; list staged 64-wide coalesced into VGPRs, broadcast
// per entry via v_readlane -> SGPR base for the x-row load.
__global__ __launch_bounds__(256) void k_gconv(const float* __restrict__ x,
        const int* __restrict__ off, const int2* __restrict__ listC,
        const float* __restrict__ dww, unsigned short* __restrict__ convb) {
    __shared__ float wsm[9 * 256];                // [tap][channel]
    int t = threadIdx.x;
#pragma unroll
    for (int k = 0; k < 9; ++k) wsm[k * 256 + t] = dww[t * 9 + k];
    int wv = t >> 6, lane = t & 63;
    int blk = blockIdx.x * 4 + wv;                // wave-uniform pixel id
    int b   = __builtin_amdgcn_readfirstlane(blk / HWo);
    int st  = __builtin_amdgcn_readfirstlane(off[NBT + blk]) - NE;
    int en  = __builtin_amdgcn_readfirstlane(off[NBT + blk + 1]) - NE;
    __syncthreads();
    const float* xb = x + (size_t)b * N * Cin;
    float4 acc = make_float4(0.f, 0.f, 0.f, 0.f);
    for (int base = st; base < en; base += 64) {
        int n = en - base; if (n > 64) n = 64;
        int2 e = make_int2(0, 0);
        if (lane < n) e = listC[base + lane];     // one coalesced 8B/lane load
        int j = 0;
        for (; j + 4 <= n; j += 4) {
            int ex0 = __builtin_amdgcn_readlane(e.x, j + 0);
            int ey0 = __builtin_amdgcn_readlane(e.y, j + 0);
            int ex1 = __builtin_amdgcn_readlane(e.x, j + 1);
            int ey1 = __builtin_amdgcn_readlane(e.y, j + 1);
            int ex2 = __builtin_amdgcn_readlane(e.x, j + 2);
            int ey2 = __builtin_amdgcn_readlane(e.y, j + 2);
            int ex3 = __builtin_amdgcn_readlane(e.x, j + 3);
            int ey3 = __builtin_amdgcn_readlane(e.y, j + 3);
            float4 v0 = ((const float4*)(xb + (size_t)(ex0 & 0xFFFF) * Cin))[lane];
            float4 v1 = ((const float4*)(xb + (size_t)(ex1 & 0xFFFF) * Cin))[lane];
            float4 v2 = ((const float4*)(xb + (size_t)(ex2 & 0xFFFF) * Cin))[lane];
            float4 v3 = ((const float4*)(xb + (size_t)(ex3 & 0xFFFF) * Cin))[lane];
            float4 w0 = *(const float4*)&wsm[(ex0 >> 16) * 256 + lane * 4];
            float4 w1 = *(const float4*)&wsm[(ex1 >> 16) * 256 + lane * 4];
            float4 w2 = *(const float4*)&wsm[(ex2 >> 16) * 256 + lane * 4];
            float4 w3 = *(const float4*)&wsm[(ex3 >> 16) * 256 + lane * 4];
            float r0 = __int_as_float(ey0), r1 = __int_as_float(ey1);
            float r2 = __int_as_float(ey2), r3 = __int_as_float(ey3);
            acc.x = fmaf(v0.x * r0, w0.x, acc.x);
            acc.y = fmaf(v0.y * r0, w0.y, acc.y);
            acc.z = fmaf(v0.z * r0, w0.z, acc.z);
            acc.w = fmaf(v0.w * r0, w0.w, acc.w);
            acc.x = fmaf(v1.x * r1, w1.x, acc.x);
            acc.y = fmaf(v1.y * r1, w1.y, acc.y);
            acc.z = fmaf(v1.z * r1, w1.z, acc.z);
            acc.w = fmaf(v1.w * r1, w1.w, acc.w);
            acc.x = fmaf(v2.x * r2, w2.x, acc.x);
            acc.y = fmaf(v2.y * r2, w2.y, acc.y);
            acc.z = fmaf(v2.z * r2, w2.z, acc.z);
            acc.w = fmaf(v2.w * r2, w2.w, acc.w);
            acc.x = fmaf(v3.x * r3, w3.x, acc.x);
            acc.y = fmaf(v3.y * r3, w3.y, acc.y);
            acc.z = fmaf(v3.z * r3, w3.z, acc.z);
            acc.w = fmaf(v3.w * r3, w3.w, acc.w);
        }
        for (; j < n; ++j) {
            int ex = __builtin_amdgcn_readlane(e.x, j);
            int ey = __builtin_amdgcn_readlane(e.y, j);
            float4 v = ((const float4*)(xb + (size_t)(ex & 0xFFFF) * Cin))[lane];
            float4 wq = *(const float4*)&wsm[(ex >> 16) * 256 + lane * 4];
            float r = __int_as_float(ey);
            acc.x = fmaf(v.x * r, wq.x, acc.x);
            acc.y = fmaf(v.y * r, wq.y, acc.y);
            acc.z = fmaf(v.z * r, wq.z, acc.z);
            acc.w = fmaf(v.w * r, wq.w, acc.w);
        }
    }
    uint2 o;
    o.x = (unsigned int)f2bf(acc.x) | ((unsigned int)f2bf(acc.y) << 16);
    o.y = (unsigned int)f2bf(acc.z) | ((unsigned int)f2bf(acc.w) << 16);
    ((uint2*)(convb + (size_t)blk * Cin))[lane] = o;
}

// ---- fused map2token + skip + BN1 partial stats: wave per token -------------
__global__ __launch_bounds__(256) void k_gtok(const float* __restrict__ x,
        const unsigned short* __restrict__ convb, const int* __restrict__ off,
        const int2* __restrict__ listT, const float* __restrict__ skipw,
        unsigned short* __restrict__ ybf, float* __restrict__ s1p,
        float* __restrict__ s1qp) {
    __shared__ float smS[4][256];
    __shared__ float smQ[4][256];
    int t = threadIdx.x, wv = t >> 6, lane = t & 63;
    int bt = blockIdx.x * 4 + wv;
    int b  = __builtin_amdgcn_readfirstlane(bt / Nt);
    int st = __builtin_amdgcn_readfirstlane(off[bt]);
    int en = __builtin_amdgcn_readfirstlane(off[bt + 1]);
    const float* xb = x + (size_t)b * N * Cin;
    const unsigned short* cbb = convb + (size_t)b * HWo * Cin;
    float4 sk = ((const float4*)skipw)[lane];
    float4 acc = make_float4(0.f, 0.f, 0.f, 0.f);
    float wsum = 0.0f;
    for (int base = st; base < en; base += 64) {
        int n = en - base; if (n > 64) n = 64;
        int2 e = make_int2(0, 0);
        if (lane < n) e = listT[base + lane];     // one coalesced 8B/lane load
        int j = 0;
        for (; j + 2 <= n; j += 2) {
            int ex0 = __builtin_amdgcn_readlane(e.x, j + 0);
            int ey0 = __builtin_amdgcn_readlane(e.y, j + 0);
            int ex1 = __builtin_amdgcn_readlane(e.x, j + 1);
            int ey1 = __builtin_amdgcn_readlane(e.y, j + 1);
            float4 xv0 = ((const float4*)(xb + (size_t)(ex0 & 0xFFFF) * Cin))[lane];
            float4 xv1 = ((const float4*)(xb + (size_t)(ex1 & 0xFFFF) * Cin))[lane];
            uint2 cv0 = ((const uint2*)(cbb + (size_t)(ex0 >> 16) * Cin))[lane];
            uint2 cv1 = ((const uint2*)(cbb + (size_t)(ex1 >> 16) * Cin))[lane];
            float w0 = __int_as_float(ey0), w1 = __int_as_float(ey1);
            wsum += w0 + w1;
            acc.x = fmaf(w0, bf2f((unsigned short)(cv0.x & 0xffffu)) + sk.x * xv0.x, acc.x);
            acc.y = fmaf(w0, bf2f((unsigned short)(cv0.x >> 16))     + sk.y * xv0.y, acc.y);
            acc.z = fmaf(w0, bf2f((unsigned short)(cv0.y & 0xffffu)) + sk.z * xv0.z, acc.z);
            acc.w = fmaf(w0, bf2f((unsigned short)(cv0.y >> 16))     + sk.w * xv0.w, acc.w);
            acc.x = fmaf(w1, bf2f((unsigned short)(cv1.x & 0xffffu)) + sk.x * xv1.x, acc.x);
            acc.y = fmaf(w1, bf2f((unsigned short)(cv1.x >> 16))     + sk.y * xv1.y, acc.y);
            acc.z = fmaf(w1, bf2f((unsigned short)(cv1.y & 0xffffu)) + sk.z * xv1.z, acc.z);
            acc.w = fmaf(w1, bf2f((unsigned short)(cv1.y >> 16))     + sk.w * xv1.w, acc.w);
        }
        for (; j < n; ++j) {
            int ex = __builtin_amdgcn_readlane(e.x, j);
            int ey = __builtin_amdgcn_readlane(e.y, j);
            float4 xv = ((const float4*)(xb + (size_t)(ex & 0xFFFF) * Cin))[lane];
            uint2 cv = ((const uint2*)(cbb + (size_t)(ex >> 16) * Cin))[lane];
            float w = __int_as_float(ey);
            wsum += w;
            acc.x = fmaf(w, bf2f((unsigned short)(cv.x & 0xffffu)) + sk.x * xv.x, acc.x);
            acc.y = fmaf(w, bf2f((unsigned short)(cv.x >> 16))     + sk.y * xv.y, acc.y);
            acc.z = fmaf(w, bf2f((unsigned short)(cv.y & 0xffffu)) + sk.z * xv.z, acc.z);
            acc.w = fmaf(w, bf2f((unsigned short)(cv.y >> 16))     + sk.w * xv.w, acc.w);
        }
    }
    float rw = 1.0f / (wsum + 1e-6f);
    float y0 = acc.x * rw, y1 = acc.y * rw, y2 = acc.z * rw, y3 = acc.w * rw;
    smS[wv][lane * 4 + 0] = y0; smQ[wv][lane * 4 + 0] = y0 * y0;
    smS[wv][lane * 4 + 1] = y1; smQ[wv][lane * 4 + 1] = y1 * y1;
    smS[wv][lane * 4 + 2] = y2; smQ[wv][lane * 4 + 2] = y2 * y2;
    smS[wv][lane * 4 + 3] = y3; smQ[wv][lane * 4 + 3] = y3 * y3;
    uint2 o;
    o.x = (unsigned int)f2bf(y0) | ((unsigned int)f2bf(y1) << 16);
    o.y = (unsigned int)f2bf(y2) | ((unsigned int)f2bf(y3) << 16);
    ((uint2*)(ybf + (size_t)bt * Cin))[lane] = o;
    __syncthreads();
    float ps = smS[0][t] + smS[1][t] + smS[2][t] + smS[3][t];
    float pq = smQ[0][t] + smQ[1][t] + smQ[2][t] + smQ[3][t];
    int g = (blockIdx.x & (NG - 1)) * Cin + t;
    atomicAdd(&s1p[g],  ps);
    atomicAdd(&s1qp[g], pq);
}

// ---- fold BN1 (reduce NG partials) into bf16 weight + fp32 bias -------------
__global__ void k_fold(const float* __restrict__ s1p, const float* __restrict__ s1qp,
                       const float* __restrict__ g1, const float* __restrict__ b1,
                       const float* __restrict__ convw, unsigned short* __restrict__ wfb,
                       float* __restrict__ bias) {
    int o = blockIdx.x, c = threadIdx.x;
    const float inv = 1.0f / (float)RR;
    float s = 0.0f, q = 0.0f;
#pragma unroll
    for (int g = 0; g < NG; ++g) { s += s1p[g * Cin + c]; q += s1qp[g * Cin + c]; }
    float mu  = s * inv;
    float var = q * inv - mu * mu;
    float a   = g1[c] / sqrtf(var + 1e-5f);
    float bs  = b1[c] - mu * a;
    float wv  = convw[(size_t)o * Cin + c];
    wfb[(size_t)o * Cin + c] = f2bf(wv * a);
    __shared__ float red[256];
    red[c] = wv * bs;
    __syncthreads();
    for (int st = 128; st > 0; st >>= 1) {
        if (c < st) red[c] += red[c + st];
        __syncthreads();
    }
    if (c == 0) bias[o] = red[0];
}

// ---- bf16 MFMA GEMM, full-K LDS residency, ONE barrier ----------------------
typedef __attribute__((ext_vector_type(8))) short short8;
typedef __attribute__((ext_vector_type(4))) float f32x4;

__global__ __launch_bounds__(256, 1) void k_gemm(const unsigned short* __restrict__ A,
        const unsigned short* __restrict__ Bt, const float* __restrict__ bias,
        unsigned short* __restrict__ zb, float* __restrict__ s2, float* __restrict__ s2q) {
    __shared__ unsigned short As[128 * 256];
    __shared__ unsigned short Bs[128 * 256];
    __shared__ float rsum[128], rsq[128];
    int m0 = blockIdx.x * 128, n0 = blockIdx.y * 128;
    int t = threadIdx.x;
    int wave = t >> 6, lane = t & 63;
    int wm = wave >> 1, wn = wave & 1;
    int l16 = lane & 15, lq = lane >> 4;
    if (t < 128) { rsum[t] = 0.0f; rsq[t] = 0.0f; }

    {
        int rlo = lane >> 5;           // 0 or 1
        int ch  = lane & 31;
#pragma unroll
        for (int p = 0; p < 16; ++p) {
            int row = wave * 32 + p * 2 + rlo;
            int sc  = ch ^ (row & 7);
            gload_lds16(A + (size_t)(m0 + row) * Cin + sc * 8,
                        &As[(wave * 32 + p * 2) * 256]);
        }
#pragma unroll
        for (int p = 0; p < 16; ++p) {
            int row = wave * 32 + p * 2 + rlo;
            int sc  = ch ^ (row & 7);
            gload_lds16(Bt + (size_t)(n0 + row) * Cin + sc * 8,
                        &Bs[(wave * 32 + p * 2) * 256]);
        }
    }
    asm volatile("s_waitcnt vmcnt(0)" ::: "memory");
    __syncthreads();

    f32x4 acc[4][4];
#pragma unroll
    for (int i = 0; i < 4; ++i)
#pragma unroll
        for (int j = 0; j < 4; ++j) acc[i][j] = (f32x4)0.0f;

#pragma unroll
    for (int ks = 0; ks < 8; ++ks) {
        short8 af[4], bf[4];
#pragma unroll
        for (int i = 0; i < 4; ++i) {
            int row = wm * 64 + i * 16 + l16;
            int c   = (ks * 4 + lq) ^ (row & 7);
            af[i] = *(short8*)&As[row * 256 + c * 8];
        }
#pragma unroll
        for (int j = 0; j < 4; ++j) {
            int row = wn * 64 + j * 16 + l16;
            int c   = (ks * 4 + lq) ^ (row & 7);
            bf[j] = *(short8*)&Bs[row * 256 + c * 8];
        }
#pragma unroll
        for (int i = 0; i < 4; ++i)
#pragma unroll
            for (int j = 0; j < 4; ++j)
                acc[i][j] = __builtin_amdgcn_mfma_f32_16x16x32_bf16(af[i], bf[j], acc[i][j], 0, 0, 0);
    }

#pragma unroll
    for (int j = 0; j < 4; ++j) {
        int cl  = wn * 64 + j * 16 + l16;
        int col = n0 + cl;
        float bv = bias[col];
        float ps = 0.0f, pq = 0.0f;
#pragma unroll
        for (int i = 0; i < 4; ++i) {
            int rbase = m0 + wm * 64 + i * 16 + lq * 4;
#pragma unroll
            for (int r = 0; r < 4; ++r) {
                float v = acc[i][j][r] + bv;
                zb[(size_t)(rbase + r) * Cout + col] = f2bf(v);
                ps += v;
                pq = fmaf(v, v, pq);
            }
        }
        atomicAdd(&rsum[cl], ps);
        atomicAdd(&rsq[cl], pq);
    }
    __syncthreads();
    if (t < 128) {
        atomicAdd(&s2[n0 + t], rsum[t]);
        atomicAdd(&s2q[n0 + t], rsq[t]);
    }
}

// ---- BN2 fold (inline) + normalize + ReLU: bf16 z -> fp32 out, 4-wide -------
__global__ void k_final(const unsigned short* __restrict__ zb,
                        const float* __restrict__ s2, const float* __restrict__ s2q,
                        const float* __restrict__ g2, const float* __restrict__ b2,
                        float* __restrict__ out) {
    size_t j4 = ((size_t)blockIdx.x * 256 + threadIdx.x) * 4;
    int o = (int)(j4 & (Cout - 1));
    const float inv = 1.0f / (float)RR;
    uint2 u = *(const uint2*)&zb[j4];
    float e0 = bf2f((unsigned short)(u.x & 0xffffu));
    float e1 = bf2f((unsigned short)(u.x >> 16));
    float e2 = bf2f((unsigned short)(u.y & 0xffffu));
    float e3 = bf2f((unsigned short)(u.y >> 16));
    float mu0 = s2[o + 0] * inv, a0 = g2[o + 0] * rsqrtf(s2q[o + 0] * inv - mu0 * mu0 + 1e-5f);
    float mu1 = s2[o + 1] * inv, a1 = g2[o + 1] * rsqrtf(s2q[o + 1] * inv - mu1 * mu1 + 1e-5f);
    float mu2 = s2[o + 2] * inv, a2 = g2[o + 2] * rsqrtf(s2q[o + 2] * inv - mu2 * mu2 + 1e-5f);
    float mu3 = s2[o + 3] * inv, a3 = g2[o + 3] * rsqrtf(s2q[o + 3] * inv - mu3 * mu3 + 1e-5f);
    float c0 = b2[o + 0] - mu0 * a0;
    float c1 = b2[o + 1] - mu1 * a1;
    float c2 = b2[o + 2] - mu2 * a2;
    float c3 = b2[o + 3] - mu3 * a3;
    float4 r;
    r.x = fmaxf(fmaf(e0, a0, c0), 0.0f);
    r.y = fmaxf(fmaf(e1, a1, c1), 0.0f);
    r.z = fmaxf(fmaf(e2, a2, c2), 0.0f);
    r.w = fmaxf(fmaf(e3, a3, c3), 0.0f);
    *(float4*)&out[j4] = r;
}

extern "C" void kernel_launch(void* const* d_in, const int* in_sizes, int n_in,
                              void* d_out, int out_size, void* d_ws, size_t ws_size,
                              hipStream_t stream) {
    const float* x     = (const float*)d_in[0];
    const float* loc   = (const float*)d_in[1];
    const int*   idxa  = (const int*)d_in[2];
    const int*   idxt  = (const int*)d_in[4];
    const float* wt    = (const float*)d_in[5];
    const float* dww   = (const float*)d_in[9];
    const float* skipw = (const float*)d_in[10];
    const float* convw = (const float*)d_in[11];
    const float* g1    = (const float*)d_in[12];
    const float* b1    = (const float*)d_in[13];
    const float* g2    = (const float*)d_in[14];
    const float* b2    = (const float*)d_in[15];

    float* ws = (float*)d_ws;
    int*   histP = (int*)(ws + W_HISTP);
    int*   histS = (int*)(ws + W_HISTS);
    float* s2sum = ws + W_S2SUM;
    float* s2sq  = ws + W_S2SQ;
    float* s1p   = ws + W_S1P;
    float* s1qp  = ws + W_S1QP;
    int*   off   = (int*)(ws + W_OFF);
    int*   cur   = (int*)(ws + W_CUR);
    int*   pc    = (int*)(ws + W_PC);
    int*   bsum  = (int*)(ws + W_BSUM);
    int2*  listT = (int2*)(ws + W_LT);
    int2*  listC = (int2*)(ws + W_LC);
    unsigned short* convb = (unsigned short*)(ws + W_CONVB);
    unsigned short* ybf   = (unsigned short*)(ws + W_YBF);
    unsigned short* wfb   = (unsigned short*)(ws + W_WFB);
    float* bias  = ws + W_BIAS;
    unsigned short* zb = (unsigned short*)(ws + W_ZB);
    float* out   = (float*)d_out;

    hipMemsetAsync(histP, 0, (size_t)W_MEND * sizeof(float), stream);

    k_hist<<<NE / 256, 256, 0, stream>>>(loc, idxt, histP, histS, pc);
    k_scanA<<<NCHUNK, 256, 0, stream>>>(histS, bsum);
    k_scanB<<<1, 512, 0, stream>>>(bsum);
    k_scanC<<<NCHUNK, 256, 0, stream>>>(histS, bsum, off, cur);
    k_scat<<<NE / 256, 256, 0, stream>>>(pc, idxa, idxt, wt, histP, cur, listT, listC);

    k_gconv<<<NBO / 4, 256, 0, stream>>>(x, off, listC, dww, convb);
    k_gtok<<<NBT / 4, 256, 0, stream>>>(x, convb, off, listT, skipw, ybf, s1p, s1qp);
    k_fold<<<Cout, 256, 0, stream>>>(s1p, s1qp, g1, b1, convw, wfb, bias);

    dim3 gg(RR / 128, Cout / 128);
    k_gemm<<<gg, 256, 0, stream>>>(ybf, wfb, bias, zb, s2sum, s2sq);
    k_final<<<(int)(((size_t)RR * Cout) / 1024), 256, 0, stream>>>(zb, s2sum, s2sq, g2, b2, out);
}

// Round 11
// 248.039 us; speedup vs baseline: 1.0314x; 1.0314x over previous
//
#include <hip/hip_runtime.h>

// Problem constants
constexpr int B    = 32;
constexpr int N    = 1568;
constexpr int N0   = 3136;
constexpr int Nt   = 784;
constexpr int Cin  = 256;
constexpr int Cout = 512;
constexpr int H    = 56;
constexpr int W    = 56;
constexpr int HW   = 3136;
constexpr int Ho   = 28;
constexpr int Wo   = 28;
constexpr int HWo  = 784;
constexpr int RR   = B * Nt;      // 25088 GEMM rows
constexpr int NE   = B * N0;      // 100352 entries per index list
constexpr int NBP  = B * HW;      // 100352 input-pixel COUNT bins (not scanned)
constexpr int NBT  = B * Nt;      // 25088 token bins   (scanned, first)
constexpr int NBO  = B * HWo;     // 25088 conv-window bins (scanned, second)
constexpr int SB   = NBT + NBO;   // 50176 scanned bins
constexpr int NCHUNK = SB / 256;  // 196
constexpr int NG   = 32;          // BN1 partial spread factor

// Workspace layout (4-byte words). hist + BN partials contiguous -> one memset.
constexpr size_t W_HISTP = 0;                          // NBP ints (zeroed)
constexpr size_t W_HISTS = NBP;                        // SB ints (zeroed)
constexpr size_t W_S2SUM = NBP + SB;                   // 512
constexpr size_t W_S2SQ  = W_S2SUM + Cout;             // 512
constexpr size_t W_S1P   = W_S2SQ + Cout;              // NG*256
constexpr size_t W_S1QP  = W_S1P + (size_t)NG * Cin;   // NG*256 (memset region ends)
constexpr size_t W_MEND  = W_S1QP + (size_t)NG * Cin;
constexpr size_t W_OFF   = W_MEND;                     // SB+1 ints (+pad)
constexpr size_t W_CUR   = W_OFF + SB + 8;             // SB ints
constexpr size_t W_PC    = W_CUR + SB;                 // NE ints (p56 | p28<<16)
constexpr size_t W_BSUM  = W_PC + NE;                  // 512 ints
constexpr size_t W_LT    = W_BSUM + 512;               // NE int2 -> 2*NE words
constexpr size_t W_LC    = W_LT + (size_t)2 * NE;      // up to 4*NE int2 -> 8*NE words
constexpr size_t W_CONVB = W_LC + (size_t)8 * NE;      // B*HWo*Cin bf16 -> /2 words
constexpr size_t W_YBF   = W_CONVB + (size_t)B * HWo * Cin / 2;  // RR*Cin bf16
constexpr size_t W_WFB   = W_YBF + (size_t)RR * Cin / 2;         // Cout*Cin bf16
constexpr size_t W_BIAS  = W_WFB + (size_t)Cout * Cin / 2;       // 512
constexpr size_t W_ZB    = W_BIAS + Cout;              // RR*Cout bf16 -> /2 words

__device__ __forceinline__ int pix_of(float t, float scale) {
    t = fminf(fmaxf(t, -1.0f), 1.0f);
    float u = __fadd_rn(__fmul_rn(t, 0.5f), 0.5f);   // no fma contraction
    return (int)rintf(__fmul_rn(u, scale));          // round-half-even == jnp.round
}
__device__ __forceinline__ unsigned short f2bf(float f) {
    unsigned int u = __float_as_uint(f);
    u = (u + 0x7fffu + ((u >> 16) & 1u)) >> 16;      // RNE
    return (unsigned short)u;
}
__device__ __forceinline__ float bf2f(unsigned short h) {
    return __uint_as_float(((unsigned int)h) << 16);
}
__device__ __forceinline__ void gload_lds16(const void* g, void* lds) {
    __builtin_amdgcn_global_load_lds(
        (const __attribute__((address_space(1))) void*)g,
        (__attribute__((address_space(3))) void*)lds, 16, 0, 0);
}

// ---- sort phase -------------------------------------------------------------
__global__ void k_hist(const float* __restrict__ loc, const int* __restrict__ idxt,
                       int* __restrict__ histP, int* __restrict__ histS,
                       int* __restrict__ pc) {
    int i = blockIdx.x * 256 + threadIdx.x;
    if (i >= NE) return;
    int b = i / N0;
    float lx = loc[(size_t)2 * i], ly = loc[(size_t)2 * i + 1];
    int ix = pix_of(lx, 55.0f), iy = pix_of(ly, 55.0f);
    int jx = pix_of(lx, 27.0f), jy = pix_of(ly, 27.0f);
    int p56 = iy * W + ix, p28 = jy * Wo + jx;
    pc[i] = p56 | (p28 << 16);
    atomicAdd(&histP[b * HW + p56], 1);
    atomicAdd(&histS[b * Nt + idxt[i]], 1);
    int oy_lo = iy >> 1, oy_hi = min(Ho - 1, (iy + 1) >> 1);
    int ox_lo = ix >> 1, ox_hi = min(Wo - 1, (ix + 1) >> 1);
    for (int oy = oy_lo; oy <= oy_hi; ++oy)
        for (int ox = ox_lo; ox <= ox_hi; ++ox)
            atomicAdd(&histS[NBT + b * HWo + oy * Wo + ox], 1);
}

__global__ void k_scanA(const int* __restrict__ hist, int* __restrict__ bsum) {
    __shared__ int sm[256];
    int i = blockIdx.x * 256 + threadIdx.x;
    sm[threadIdx.x] = hist[i];
    __syncthreads();
    for (int d = 128; d > 0; d >>= 1) {
        if (threadIdx.x < d) sm[threadIdx.x] += sm[threadIdx.x + d];
        __syncthreads();
    }
    if (threadIdx.x == 0) bsum[blockIdx.x] = sm[0];
}

__global__ void k_scanB(int* __restrict__ bsum) {
    __shared__ int sm[512];
    int t = threadIdx.x;
    int v = (t < NCHUNK) ? bsum[t] : 0;
    sm[t] = v; __syncthreads();
    for (int d = 1; d < 512; d <<= 1) {
        int u = (t >= d) ? sm[t - d] : 0;
        __syncthreads();
        sm[t] += u;
        __syncthreads();
    }
    if (t < NCHUNK) bsum[t] = sm[t] - v;
}

__global__ void k_scanC(const int* __restrict__ hist, const int* __restrict__ bsum,
                        int* __restrict__ off, int* __restrict__ cur) {
    __shared__ int sm[256];
    int t = threadIdx.x;
    int i = blockIdx.x * 256 + t;
    int v = hist[i];
    sm[t] = v; __syncthreads();
    for (int d = 1; d < 256; d <<= 1) {
        int u = (t >= d) ? sm[t - d] : 0;
        __syncthreads();
        sm[t] += u;
        __syncthreads();
    }
    int excl = bsum[blockIdx.x] + sm[t] - v;
    off[i] = excl; cur[i] = excl;
    if (i == SB - 1) off[SB] = excl + v;
}

__global__ void k_scat(const int* __restrict__ pc, const int* __restrict__ idxa,
                       const int* __restrict__ idxt, const float* __restrict__ wt,
                       const int* __restrict__ histP, int* __restrict__ cur,
                       int2* __restrict__ listT, int2* __restrict__ listC) {
    int i = blockIdx.x * 256 + threadIdx.x;
    if (i >= NE) return;
    int b = i / N0;
    int v = pc[i];
    int p56 = v & 0xFFFF, p28 = v >> 16;
    int s = idxa[i];
    int posT = atomicAdd(&cur[b * Nt + idxt[i]], 1);
    listT[posT] = make_int2(s | (p28 << 16), __float_as_int(wt[i]));
    float wrc = 1.0f / ((float)histP[b * HW + p56] + 1e-6f);
    int wrci = __float_as_int(wrc);
    int iy = p56 / W, ix = p56 - iy * W;
    int oy_lo = iy >> 1, oy_hi = min(Ho - 1, (iy + 1) >> 1);
    int ox_lo = ix >> 1, ox_hi = min(Wo - 1, (ix + 1) >> 1);
    for (int oy = oy_lo; oy <= oy_hi; ++oy)
        for (int ox = ox_lo; ox <= ox_hi; ++ox) {
            int tap = (iy - (2 * oy - 1)) * 3 + (ix - (2 * ox - 1));
            int posC = atomicAdd(&cur[NBT + b * HWo + oy * Wo + ox], 1) - NE;
            listC[posC] = make_int2(s | (tap << 16), wrci);
        }
}

// ---- fused token2map + 3x3 dw s2 conv ---------------------------------------
__global__ __launch_bounds__(256) void k_gconv(const float* __restrict__ x,
        const int* __restrict__ off, const int2* __restrict__ listC,
        const float* __restrict__ dww, unsigned short* __restrict__ convb) {
    __shared__ float wsm[9 * 256];                // [tap][channel]
    int t = threadIdx.x;
#pragma unroll
    for (int k = 0; k < 9; ++k) wsm[k * 256 + t] = dww[t * 9 + k];
    int wv = t >> 6, lane = t & 63;
    int blk = blockIdx.x * 4 + wv;                // wave-uniform pixel id
    int b   = __builtin_amdgcn_readfirstlane(blk / HWo);
    int st  = __builtin_amdgcn_readfirstlane(off[NBT + blk]) - NE;
    int en  = __builtin_amdgcn_readfirstlane(off[NBT + blk + 1]) - NE;
    __syncthreads();
    const float* xb = x + (size_t)b * N * Cin;
    float4 acc = make_float4(0.f, 0.f, 0.f, 0.f);
    for (int base = st; base < en; base += 64) {
        int n = en - base; if (n > 64) n = 64;
        int2 e = make_int2(0, 0);
        if (lane < n) e = listC[base + lane];     // one coalesced 8B/lane load
        int j = 0;
        for (; j + 4 <= n; j += 4) {
            int ex0 = __builtin_amdgcn_readlane(e.x, j + 0);
            int ey0 = __builtin_amdgcn_readlane(e.y, j + 0);
            int ex1 = __builtin_amdgcn_readlane(e.x, j + 1);
            int ey1 = __builtin_amdgcn_readlane(e.y, j + 1);
            int ex2 = __builtin_amdgcn_readlane(e.x, j + 2);
            int ey2 = __builtin_amdgcn_readlane(e.y, j + 2);
            int ex3 = __builtin_amdgcn_readlane(e.x, j + 3);
            int ey3 = __builtin_amdgcn_readlane(e.y, j + 3);
            float4 v0 = ((const float4*)(xb + (size_t)(ex0 & 0xFFFF) * Cin))[lane];
            float4 v1 = ((const float4*)(xb + (size_t)(ex1 & 0xFFFF) * Cin))[lane];
            float4 v2 = ((const float4*)(xb + (size_t)(ex2 & 0xFFFF) * Cin))[lane];
            float4 v3 = ((const float4*)(xb + (size_t)(ex3 & 0xFFFF) * Cin))[lane];
            float4 w0 = *(const float4*)&wsm[(ex0 >> 16) * 256 + lane * 4];
            float4 w1 = *(const float4*)&wsm[(ex1 >> 16) * 256 + lane * 4];
            float4 w2 = *(const float4*)&wsm[(ex2 >> 16) * 256 + lane * 4];
            float4 w3 = *(const float4*)&wsm[(ex3 >> 16) * 256 + lane * 4];
            float r0 = __int_as_float(ey0), r1 = __int_as_float(ey1);
            float r2 = __int_as_float(ey2), r3 = __int_as_float(ey3);
            acc.x = fmaf(v0.x * r0, w0.x, acc.x);
            acc.y = fmaf(v0.y * r0, w0.y, acc.y);
            acc.z = fmaf(v0.z * r0, w0.z, acc.z);
            acc.w = fmaf(v0.w * r0, w0.w, acc.w);
            acc.x = fmaf(v1.x * r1, w1.x, acc.x);
            acc.y = fmaf(v1.y * r1, w1.y, acc.y);
            acc.z = fmaf(v1.z * r1, w1.z, acc.z);
            acc.w = fmaf(v1.w * r1, w1.w, acc.w);
            acc.x = fmaf(v2.x * r2, w2.x, acc.x);
            acc.y = fmaf(v2.y * r2, w2.y, acc.y);
            acc.z = fmaf(v2.z * r2, w2.z, acc.z);
            acc.w = fmaf(v2.w * r2, w2.w, acc.w);
            acc.x = fmaf(v3.x * r3, w3.x, acc.x);
            acc.y = fmaf(v3.y * r3, w3.y, acc.y);
            acc.z = fmaf(v3.z * r3, w3.z, acc.z);
            acc.w = fmaf(v3.w * r3, w3.w, acc.w);
        }
        for (; j < n; ++j) {
            int ex = __builtin_amdgcn_readlane(e.x, j);
            int ey = __builtin_amdgcn_readlane(e.y, j);
            float4 v = ((const float4*)(xb + (size_t)(ex & 0xFFFF) * Cin))[lane];
            float4 wq = *(const float4*)&wsm[(ex >> 16) * 256 + lane * 4];
            float r = __int_as_float(ey);
            acc.x = fmaf(v.x * r, wq.x, acc.x);
            acc.y = fmaf(v.y * r, wq.y, acc.y);
            acc.z = fmaf(v.z * r, wq.z, acc.z);
            acc.w = fmaf(v.w * r, wq.w, acc.w);
        }
    }
    uint2 o;
    o.x = (unsigned int)f2bf(acc.x) | ((unsigned int)f2bf(acc.y) << 16);
    o.y = (unsigned int)f2bf(acc.z) | ((unsigned int)f2bf(acc.w) << 16);
    ((uint2*)(convb + (size_t)blk * Cin))[lane] = o;
}

// ---- fused map2token + skip + BN1 partial stats: wave per token -------------
__global__ __launch_bounds__(256) void k_gtok(const float* __restrict__ x,
        const unsigned short* __restrict__ convb, const int* __restrict__ off,
        const int2* __restrict__ listT, const float* __restrict__ skipw,
        unsigned short* __restrict__ ybf, float* __restrict__ s1p,
        float* __restrict__ s1qp) {
    __shared__ float smS[4][256];
    __shared__ float smQ[4][256];
    int t = threadIdx.x, wv = t >> 6, lane = t & 63;
    int bt = blockIdx.x * 4 + wv;
    int b  = __builtin_amdgcn_readfirstlane(bt / Nt);
    int st = __builtin_amdgcn_readfirstlane(off[bt]);
    int en = __builtin_amdgcn_readfirstlane(off[bt + 1]);
    const float* xb = x + (size_t)b * N * Cin;
    const unsigned short* cbb = convb + (size_t)b * HWo * Cin;
    float4 sk = ((const float4*)skipw)[lane];
    float4 acc = make_float4(0.f, 0.f, 0.f, 0.f);
    float wsum = 0.0f;
    for (int base = st; base < en; base += 64) {
        int n = en - base; if (n > 64) n = 64;
        int2 e = make_int2(0, 0);
        if (lane < n) e = listT[base + lane];     // one coalesced 8B/lane load
        int j = 0;
        for (; j + 2 <= n; j += 2) {
            int ex0 = __builtin_amdgcn_readlane(e.x, j + 0);
            int ey0 = __builtin_amdgcn_readlane(e.y, j + 0);
            int ex1 = __builtin_amdgcn_readlane(e.x, j + 1);
            int ey1 = __builtin_amdgcn_readlane(e.y, j + 1);
            float4 xv0 = ((const float4*)(xb + (size_t)(ex0 & 0xFFFF) * Cin))[lane];
            float4 xv1 = ((const float4*)(xb + (size_t)(ex1 & 0xFFFF) * Cin))[lane];
            uint2 cv0 = ((const uint2*)(cbb + (size_t)(ex0 >> 16) * Cin))[lane];
            uint2 cv1 = ((const uint2*)(cbb + (size_t)(ex1 >> 16) * Cin))[lane];
            float w0 = __int_as_float(ey0), w1 = __int_as_float(ey1);
            wsum += w0 + w1;
            acc.x = fmaf(w0, bf2f((unsigned short)(cv0.x & 0xffffu)) + sk.x * xv0.x, acc.x);
            acc.y = fmaf(w0, bf2f((unsigned short)(cv0.x >> 16))     + sk.y * xv0.y, acc.y);
            acc.z = fmaf(w0, bf2f((unsigned short)(cv0.y & 0xffffu)) + sk.z * xv0.z, acc.z);
            acc.w = fmaf(w0, bf2f((unsigned short)(cv0.y >> 16))     + sk.w * xv0.w, acc.w);
            acc.x = fmaf(w1, bf2f((unsigned short)(cv1.x & 0xffffu)) + sk.x * xv1.x, acc.x);
            acc.y = fmaf(w1, bf2f((unsigned short)(cv1.x >> 16))     + sk.y * xv1.y, acc.y);
            acc.z = fmaf(w1, bf2f((unsigned short)(cv1.y & 0xffffu)) + sk.z * xv1.z, acc.z);
            acc.w = fmaf(w1, bf2f((unsigned short)(cv1.y >> 16))     + sk.w * xv1.w, acc.w);
        }
        for (; j < n; ++j) {
            int ex = __builtin_amdgcn_readlane(e.x, j);
            int ey = __builtin_amdgcn_readlane(e.y, j);
            float4 xv = ((const float4*)(xb + (size_t)(ex & 0xFFFF) * Cin))[lane];
            uint2 cv = ((const uint2*)(cbb + (size_t)(ex >> 16) * Cin))[lane];
            float w = __int_as_float(ey);
            wsum += w;
            acc.x = fmaf(w, bf2f((unsigned short)(cv.x & 0xffffu)) + sk.x * xv.x, acc.x);
            acc.y = fmaf(w, bf2f((unsigned short)(cv.x >> 16))     + sk.y * xv.y, acc.y);
            acc.z = fmaf(w, bf2f((unsigned short)(cv.y & 0xffffu)) + sk.z * xv.z, acc.z);
            acc.w = fmaf(w, bf2f((unsigned short)(cv.y >> 16))     + sk.w * xv.w, acc.w);
        }
    }
    float rw = 1.0f / (wsum + 1e-6f);
    float y0 = acc.x * rw, y1 = acc.y * rw, y2 = acc.z * rw, y3 = acc.w * rw;
    smS[wv][lane * 4 + 0] = y0; smQ[wv][lane * 4 + 0] = y0 * y0;
    smS[wv][lane * 4 + 1] = y1; smQ[wv][lane * 4 + 1] = y1 * y1;
    smS[wv][lane * 4 + 2] = y2; smQ[wv][lane * 4 + 2] = y2 * y2;
    smS[wv][lane * 4 + 3] = y3; smQ[wv][lane * 4 + 3] = y3 * y3;
    uint2 o;
    o.x = (unsigned int)f2bf(y0) | ((unsigned int)f2bf(y1) << 16);
    o.y = (unsigned int)f2bf(y2) | ((unsigned int)f2bf(y3) << 16);
    ((uint2*)(ybf + (size_t)bt * Cin))[lane] = o;
    __syncthreads();
    float ps = smS[0][t] + smS[1][t] + smS[2][t] + smS[3][t];
    float pq = smQ[0][t] + smQ[1][t] + smQ[2][t] + smQ[3][t];
    int g = (blockIdx.x & (NG - 1)) * Cin + t;
    atomicAdd(&s1p[g],  ps);
    atomicAdd(&s1qp[g], pq);
}

// ---- fold BN1 (reduce NG partials) into bf16 weight + fp32 bias -------------
__global__ void k_fold(const float* __restrict__ s1p, const float* __restrict__ s1qp,
                       const float* __restrict__ g1, const float* __restrict__ b1,
                       const float* __restrict__ convw, unsigned short* __restrict__ wfb,
                       float* __restrict__ bias) {
    int o = blockIdx.x, c = threadIdx.x;
    const float inv = 1.0f / (float)RR;
    float s = 0.0f, q = 0.0f;
#pragma unroll
    for (int g = 0; g < NG; ++g) { s += s1p[g * Cin + c]; q += s1qp[g * Cin + c]; }
    float mu  = s * inv;
    float var = q * inv - mu * mu;
    float a   = g1[c] / sqrtf(var + 1e-5f);
    float bs  = b1[c] - mu * a;
    float wv  = convw[(size_t)o * Cin + c];
    wfb[(size_t)o * Cin + c] = f2bf(wv * a);
    __shared__ float red[256];
    red[c] = wv * bs;
    __syncthreads();
    for (int st = 128; st > 0; st >>= 1) {
        if (c < st) red[c] += red[c + st];
        __syncthreads();
    }
    if (c == 0) bias[o] = red[0];
}

// ---- bf16 MFMA GEMM: BK=32 double-buffered gload_lds, __syncthreads loop ----
// 128x128 tile, LDS 2x(8KB A + 8KB B) = 32KB -> 4 blocks/CU.
// One __syncthreads per K-step: its implicit vmcnt(0)+lgkmcnt(0) drain both
// publishes the prefetched buffer and retires all reads (m97-verified pattern).
// LDS chunk-XOR swizzle key (row>>2)&3: linear dest + permuted source +
// swizzled read -> 2-way bank aliasing = free.
typedef __attribute__((ext_vector_type(8))) short short8;
typedef __attribute__((ext_vector_type(4))) float f32x4;

__global__ __launch_bounds__(256, 4) void k_gemm(const unsigned short* __restrict__ A,
        const unsigned short* __restrict__ Bt, const float* __restrict__ bias,
        unsigned short* __restrict__ zb, float* __restrict__ s2, float* __restrict__ s2q) {
    __shared__ unsigned short As[2][128 * 32];
    __shared__ unsigned short Bs[2][128 * 32];
    __shared__ float rsum[128], rsq[128];
    int m0 = blockIdx.x * 128, n0 = blockIdx.y * 128;
    int t = threadIdx.x;
    int wave = t >> 6, lane = t & 63;
    int wm = wave >> 1, wn = wave & 1;
    int l16 = lane & 15, lq = lane >> 4;
    if (t < 128) { rsum[t] = 0.0f; rsq[t] = 0.0f; }

    // stage addressing: lane -> row_off = lane>>2 (16 rows/instr), chunk = lane&3
    // source chunk sc = (lane&3) ^ ((lane>>4)&3)  [key = bits 3:2 of row]
    int r_off = lane >> 2;
    int sc    = (lane & 3) ^ ((lane >> 4) & 3);
    const unsigned short* Asrc = A  + (size_t)(m0 + r_off) * Cin + sc * 8;
    const unsigned short* Bsrc = Bt + (size_t)(n0 + r_off) * Cin + sc * 8;
    int r0a = wave * 32, r0b = r0a + 16;

    auto STAGE = [&](int buf, int k0) {
        gload_lds16(Asrc + (size_t)r0a * Cin + k0, &As[buf][r0a * 32]);
        gload_lds16(Asrc + (size_t)r0b * Cin + k0, &As[buf][r0b * 32]);
        gload_lds16(Bsrc + (size_t)r0a * Cin + k0, &Bs[buf][r0a * 32]);
        gload_lds16(Bsrc + (size_t)r0b * Cin + k0, &Bs[buf][r0b * 32]);
    };

    // read-side LDS offsets (ushort units): row*32 + (lq^((l16>>2)&3))*8
    int ckoff = (lq ^ ((l16 >> 2) & 3)) * 8;
    int rbA = (wm * 64 + l16) * 32 + ckoff;
    int rbB = (wn * 64 + l16) * 32 + ckoff;

    f32x4 acc[4][4];
#pragma unroll
    for (int i = 0; i < 4; ++i)
#pragma unroll
        for (int j = 0; j < 4; ++j) acc[i][j] = (f32x4)0.0f;

    STAGE(0, 0);
    __syncthreads();                       // drains vmcnt(0): buf0 published
#pragma unroll
    for (int ks = 0; ks < 8; ++ks) {
        int cur = ks & 1;
        if (ks < 7) STAGE(cur ^ 1, (ks + 1) * 32);   // prefetch next under compute
        short8 af[4], bf[4];
#pragma unroll
        for (int i = 0; i < 4; ++i) af[i] = *(short8*)&As[cur][rbA + i * 512];
#pragma unroll
        for (int j = 0; j < 4; ++j) bf[j] = *(short8*)&Bs[cur][rbB + j * 512];
#pragma unroll
        for (int i = 0; i < 4; ++i)
#pragma unroll
            for (int j = 0; j < 4; ++j)
                acc[i][j] = __builtin_amdgcn_mfma_f32_16x16x32_bf16(af[i], bf[j], acc[i][j], 0, 0, 0);
        __syncthreads();                   // publishes next buf + retires reads
    }

    // epilogue: bias add, bf16 z store, fused BN2 partial stats
#pragma unroll
    for (int j = 0; j < 4; ++j) {
        int cl  = wn * 64 + j * 16 + l16;
        int col = n0 + cl;
        float bv = bias[col];
        float ps = 0.0f, pq = 0.0f;
#pragma unroll
        for (int i = 0; i < 4; ++i) {
            int rbase = m0 + wm * 64 + i * 16 + lq * 4;
#pragma unroll
            for (int r = 0; r < 4; ++r) {
                float v = acc[i][j][r] + bv;
                zb[(size_t)(rbase + r) * Cout + col] = f2bf(v);
                ps += v;
                pq = fmaf(v, v, pq);
            }
        }
        atomicAdd(&rsum[cl], ps);
        atomicAdd(&rsq[cl], pq);
    }
    __syncthreads();
    if (t < 128) {
        atomicAdd(&s2[n0 + t], rsum[t]);
        atomicAdd(&s2q[n0 + t], rsq[t]);
    }
}

// ---- BN2 fold (inline) + normalize + ReLU: bf16 z -> fp32 out, 4-wide -------
__global__ void k_final(const unsigned short* __restrict__ zb,
                        const float* __restrict__ s2, const float* __restrict__ s2q,
                        const float* __restrict__ g2, const float* __restrict__ b2,
                        float* __restrict__ out) {
    size_t j4 = ((size_t)blockIdx.x * 256 + threadIdx.x) * 4;
    int o = (int)(j4 & (Cout - 1));
    const float inv = 1.0f / (float)RR;
    uint2 u = *(const uint2*)&zb[j4];
    float e0 = bf2f((unsigned short)(u.x & 0xffffu));
    float e1 = bf2f((unsigned short)(u.x >> 16));
    float e2 = bf2f((unsigned short)(u.y & 0xffffu));
    float e3 = bf2f((unsigned short)(u.y >> 16));
    float mu0 = s2[o + 0] * inv, a0 = g2[o + 0] * rsqrtf(s2q[o + 0] * inv - mu0 * mu0 + 1e-5f);
    float mu1 = s2[o + 1] * inv, a1 = g2[o + 1] * rsqrtf(s2q[o + 1] * inv - mu1 * mu1 + 1e-5f);
    float mu2 = s2[o + 2] * inv, a2 = g2[o + 2] * rsqrtf(s2q[o + 2] * inv - mu2 * mu2 + 1e-5f);
    float mu3 = s2[o + 3] * inv, a3 = g2[o + 3] * rsqrtf(s2q[o + 3] * inv - mu3 * mu3 + 1e-5f);
    float c0 = b2[o + 0] - mu0 * a0;
    float c1 = b2[o + 1] - mu1 * a1;
    float c2 = b2[o + 2] - mu2 * a2;
    float c3 = b2[o + 3] - mu3 * a3;
    float4 r;
    r.x = fmaxf(fmaf(e0, a0, c0), 0.0f);
    r.y = fmaxf(fmaf(e1, a1, c1), 0.0f);
    r.z = fmaxf(fmaf(e2, a2, c2), 0.0f);
    r.w = fmaxf(fmaf(e3, a3, c3), 0.0f);
    *(float4*)&out[j4] = r;
}

extern "C" void kernel_launch(void* const* d_in, const int* in_sizes, int n_in,
                              void* d_out, int out_size, void* d_ws, size_t ws_size,
                              hipStream_t stream) {
    const float* x     = (const float*)d_in[0];
    const float* loc   = (const float*)d_in[1];
    const int*   idxa  = (const int*)d_in[2];
    const int*   idxt  = (const int*)d_in[4];
    const float* wt    = (const float*)d_in[5];
    const float* dww   = (const float*)d_in[9];
    const float* skipw = (const float*)d_in[10];
    const float* convw = (const float*)d_in[11];
    const float* g1    = (const float*)d_in[12];
    const float* b1    = (const float*)d_in[13];
    const float* g2    = (const float*)d_in[14];
    const float* b2    = (const float*)d_in[15];

    float* ws = (float*)d_ws;
    int*   histP = (int*)(ws + W_HISTP);
    int*   histS = (int*)(ws + W_HISTS);
    float* s2sum = ws + W_S2SUM;
    float* s2sq  = ws + W_S2SQ;
    float* s1p   = ws + W_S1P;
    float* s1qp  = ws + W_S1QP;
    int*   off   = (int*)(ws + W_OFF);
    int*   cur   = (int*)(ws + W_CUR);
    int*   pc    = (int*)(ws + W_PC);
    int*   bsum  = (int*)(ws + W_BSUM);
    int2*  listT = (int2*)(ws + W_LT);
    int2*  listC = (int2*)(ws + W_LC);
    unsigned short* convb = (unsigned short*)(ws + W_CONVB);
    unsigned short* ybf   = (unsigned short*)(ws + W_YBF);
    unsigned short* wfb   = (unsigned short*)(ws + W_WFB);
    float* bias  = ws + W_BIAS;
    unsigned short* zb = (unsigned short*)(ws + W_ZB);
    float* out   = (float*)d_out;

    hipMemsetAsync(histP, 0, (size_t)W_MEND * sizeof(float), stream);

    k_hist<<<NE / 256, 256, 0, stream>>>(loc, idxt, histP, histS, pc);
    k_scanA<<<NCHUNK, 256, 0, stream>>>(histS, bsum);
    k_scanB<<<1, 512, 0, stream>>>(bsum);
    k_scanC<<<NCHUNK, 256, 0, stream>>>(histS, bsum, off, cur);
    k_scat<<<NE / 256, 256, 0, stream>>>(pc, idxa, idxt, wt, histP, cur, listT, listC);

    k_gconv<<<NBO / 4, 256, 0, stream>>>(x, off, listC, dww, convb);
    k_gtok<<<NBT / 4, 256, 0, stream>>>(x, convb, off, listT, skipw, ybf, s1p, s1qp);
    k_fold<<<Cout, 256, 0, stream>>>(s1p, s1qp, g1, b1, convw, wfb, bias);

    dim3 gg(RR / 128, Cout / 128);
    k_gemm<<<gg, 256, 0, stream>>>(ybf, wfb, bias, zb, s2sum, s2sq);
    k_final<<<(int)(((size_t)RR * Cout) / 1024), 256, 0, stream>>>(zb, s2sum, s2sq, g2, b2, out);
}